// Round 1
// baseline (674.935 us; speedup 1.0000x reference)
//
#include <hip/hip_runtime.h>
#include <hip/hip_bf16.h>

// MergedLinearFormer: out = softmax((x@QK)@x^T / sqrt(D)) @ x @ VO
// B=4, T=4096, D=1024. All matmuls via bf16 MFMA 16x16x32, f32 accumulate.

#define BB 4
#define TT 4096
#define DD 1024

typedef __attribute__((ext_vector_type(8))) short bf16x8;
typedef __attribute__((ext_vector_type(4))) float f32x4;

__device__ __forceinline__ void gll16(const void* g, void* l) {
  // async global->LDS, 16B/lane, LDS dest = wave-uniform base + lane*16
  __builtin_amdgcn_global_load_lds(
      (__attribute__((address_space(1))) void*)g,
      (__attribute__((address_space(3))) void*)l, 16, 0, 0);
}

// ---------------- cast f32 -> bf16 (vectorized, 8 elems/thread) -------------
__global__ __launch_bounds__(256) void cast_bf16_k(const float* __restrict__ in,
                                                   __hip_bfloat16* __restrict__ out,
                                                   long n) {
  long i = ((long)blockIdx.x * 256 + threadIdx.x) * 8;
  if (i + 8 > n) return;
  float4 f0 = *(const float4*)(in + i);
  float4 f1 = *(const float4*)(in + i + 4);
  union { __hip_bfloat16 h[8]; uint4 v; } u;
  u.h[0] = __float2bfloat16(f0.x); u.h[1] = __float2bfloat16(f0.y);
  u.h[2] = __float2bfloat16(f0.z); u.h[3] = __float2bfloat16(f0.w);
  u.h[4] = __float2bfloat16(f1.x); u.h[5] = __float2bfloat16(f1.y);
  u.h[6] = __float2bfloat16(f1.z); u.h[7] = __float2bfloat16(f1.w);
  *(uint4*)(out + i) = u.v;
}

// ------------- transpose + cast: in f32 [R][C] -> out bf16 [C][R] -----------
__global__ __launch_bounds__(256) void transpose_cast_k(const float* __restrict__ in,
                                                        __hip_bfloat16* __restrict__ out,
                                                        int R, int C,
                                                        long in_bstride, long out_bstride) {
  in  += (long)blockIdx.z * in_bstride;
  out += (long)blockIdx.z * out_bstride;
  __shared__ __hip_bfloat16 tile[64][65];
  int c0 = blockIdx.x * 64, r0 = blockIdx.y * 64;
  int tx = threadIdx.x & 63, ty = threadIdx.x >> 6;
#pragma unroll
  for (int i = 0; i < 16; ++i) {
    int r = ty + i * 4;
    tile[r][tx] = __float2bfloat16(in[(long)(r0 + r) * C + c0 + tx]);
  }
  __syncthreads();
#pragma unroll
  for (int i = 0; i < 16; ++i) {
    int c = ty + i * 4;
    out[(long)(c0 + c) * R + r0 + tx] = tile[tx][c];
  }
}

// ---------------- GEMM: C[M,N] = alpha * A[M,K] @ Bt[N,K]^T -----------------
// m97-style: 128x128 tile, BK=32, 256 thr (4 waves 2x2), 4x4 16x16x32 frags/wave.
template <typename OUT_T>
__global__ __launch_bounds__(256, 2) void gemm_bt(
    const __hip_bfloat16* __restrict__ A,
    const __hip_bfloat16* __restrict__ Bt,
    OUT_T* __restrict__ C,
    int M, int N, int K, float alpha) {
  __shared__ __hip_bfloat16 As[128 * 32];
  __shared__ __hip_bfloat16 Bs[128 * 32];

  const int tid = threadIdx.x;
  const int lane = tid & 63;
  const int wid = tid >> 6;
  const int wr = wid >> 1;          // wave row (0..1)
  const int wc = wid & 1;           // wave col (0..1)

  const long m0 = (long)blockIdx.x * 128;
  const long n0 = (long)blockIdx.y * 128;

  // staging: thread tid loads 8 contiguous bf16; tile row = tid/4, col = (tid&3)*8
  const int s_row = tid >> 2;
  const int s_col = (tid & 3) * 8;

  const int fr = lane & 15;          // fragment M/N index
  const int fk = (lane >> 4) * 8;    // fragment K offset (8 contiguous)

  f32x4 acc[4][4];
#pragma unroll
  for (int m = 0; m < 4; ++m)
#pragma unroll
    for (int n = 0; n < 4; ++n)
      acc[m][n] = (f32x4){0.f, 0.f, 0.f, 0.f};

  const __hip_bfloat16* Abase = A + (m0 + s_row) * (long)K + s_col;
  const __hip_bfloat16* Bbase = Bt + (n0 + s_row) * (long)K + s_col;
  __hip_bfloat16* AsW = As + (size_t)wid * 64 * 8;   // wave-uniform LDS base
  __hip_bfloat16* BsW = Bs + (size_t)wid * 64 * 8;

  for (int k0 = 0; k0 < K; k0 += 32) {
    if (k0) __syncthreads();   // LDS reads of prev tile done before overwrite
    gll16(Abase + k0,                  AsW);
    gll16(Abase + 64 * (long)K + k0,   AsW + 256 * 8);
    gll16(Bbase + k0,                  BsW);
    gll16(Bbase + 64 * (long)K + k0,   BsW + 256 * 8);
    __syncthreads();           // compiler drains vmcnt(0) before s_barrier

    bf16x8 a[4], b[4];
#pragma unroll
    for (int m = 0; m < 4; ++m)
      a[m] = *(const bf16x8*)(As + (wr * 64 + m * 16 + fr) * 32 + fk);
#pragma unroll
    for (int n = 0; n < 4; ++n)
      b[n] = *(const bf16x8*)(Bs + (wc * 64 + n * 16 + fr) * 32 + fk);

#pragma unroll
    for (int m = 0; m < 4; ++m)
#pragma unroll
      for (int n = 0; n < 4; ++n)
        acc[m][n] = __builtin_amdgcn_mfma_f32_16x16x32_bf16(a[m], b[n], acc[m][n], 0, 0, 0);
  }

  // epilogue: C/D layout col=lane&15, row=(lane>>4)*4+reg  [verified m89]
#pragma unroll
  for (int m = 0; m < 4; ++m) {
#pragma unroll
    for (int n = 0; n < 4; ++n) {
#pragma unroll
      for (int r = 0; r < 4; ++r) {
        long row = m0 + wr * 64 + m * 16 + (lane >> 4) * 4 + r;
        long col = n0 + wc * 64 + n * 16 + fr;
        float v = acc[m][n][r] * alpha;
        if constexpr (sizeof(OUT_T) == 4)
          C[row * N + col] = v;
        else
          C[row * N + col] = __float2bfloat16(v);
      }
    }
  }
}

// ------------- row softmax: scores f32 [T][T] -> attn bf16 [T][T] -----------
__global__ __launch_bounds__(256) void softmax_rows_k(const float* __restrict__ S,
                                                      __hip_bfloat16* __restrict__ P,
                                                      int T) {
  const long row = blockIdx.x;
  const float* s = S + row * (long)T;
  __hip_bfloat16* p = P + row * (long)T;
  const int tid = threadIdx.x;
  __shared__ float red[8];

  float v[16];
  float m = -1e30f;
#pragma unroll
  for (int i = 0; i < 16; ++i) {
    v[i] = s[tid + i * 256];
    m = fmaxf(m, v[i]);
  }
#pragma unroll
  for (int off = 32; off >= 1; off >>= 1) m = fmaxf(m, __shfl_xor(m, off));
  if ((tid & 63) == 0) red[tid >> 6] = m;
  __syncthreads();
  m = fmaxf(fmaxf(red[0], red[1]), fmaxf(red[2], red[3]));

  float l = 0.f;
#pragma unroll
  for (int i = 0; i < 16; ++i) {
    v[i] = __expf(v[i] - m);
    l += v[i];
  }
#pragma unroll
  for (int off = 32; off >= 1; off >>= 1) l += __shfl_xor(l, off);
  if ((tid & 63) == 0) red[4 + (tid >> 6)] = l;
  __syncthreads();
  l = red[4] + red[5] + red[6] + red[7];
  const float inv = 1.0f / l;
#pragma unroll
  for (int i = 0; i < 16; ++i)
    p[tid + i * 256] = __float2bfloat16(v[i] * inv);
}

// ------------------------------- launch -------------------------------------
extern "C" void kernel_launch(void* const* d_in, const int* in_sizes, int n_in,
                              void* d_out, int out_size, void* d_ws, size_t ws_size,
                              hipStream_t stream) {
  const float* x  = (const float*)d_in[0];
  const float* QK = (const float*)d_in[1];
  const float* VO = (const float*)d_in[2];
  float* out = (float*)d_out;
  char* ws = (char*)d_ws;

  const long MB = 1l << 20;
  __hip_bfloat16* QKT  = (__hip_bfloat16*)(ws);             //   2 MB  [D][D] = QK^T
  __hip_bfloat16* VOT  = (__hip_bfloat16*)(ws + 2 * MB);    //   2 MB  [D][D] = VO^T
  __hip_bfloat16* xb   = (__hip_bfloat16*)(ws + 4 * MB);    //  32 MB  [B,T,D]
  __hip_bfloat16* xT   = (__hip_bfloat16*)(ws + 36 * MB);   //  32 MB  [B,D,T]
  __hip_bfloat16* xqk  = (__hip_bfloat16*)(ws + 68 * MB);   //  32 MB  [B,T,D]; reused as av
  __hip_bfloat16* attn = (__hip_bfloat16*)(ws + 100 * MB);  //  32 MB  [T,T] per batch
  float* scores        = (float*)(ws + 132 * MB);           //  64 MB  [T,T] per batch
  // total: 196 MB

  const long NTOK = (long)BB * TT;        // 16384
  const long bstride = (long)TT * DD;     // per-batch elements

  // 1) x -> bf16 (row-major)
  cast_bf16_k<<<(int)(NTOK * DD / (256 * 8)), 256, 0, stream>>>(x, xb, NTOK * DD);
  // 2) weight transposes: QKT[e][d]=QK[d][e], VOT[e][d]=VO[d][e]
  transpose_cast_k<<<dim3(16, 16, 1), 256, 0, stream>>>(QK, QKT, DD, DD, 0, 0);
  transpose_cast_k<<<dim3(16, 16, 1), 256, 0, stream>>>(VO, VOT, DD, DD, 0, 0);
  // 3) xT[b][d][t] = x[b][t][d]
  transpose_cast_k<<<dim3(DD / 64, TT / 64, BB), 256, 0, stream>>>(x, xT, TT, DD, bstride, bstride);
  // 4) xqk = x @ QK   (A=xb [16384,1024], Bt=QKT [1024,1024])
  gemm_bt<__hip_bfloat16><<<dim3(NTOK / 128, DD / 128), 256, 0, stream>>>(
      xb, QKT, xqk, (int)NTOK, DD, DD, 1.0f);

  for (int b = 0; b < BB; ++b) {
    const __hip_bfloat16* xqk_b = xqk + b * bstride;
    const __hip_bfloat16* xb_b  = xb + b * bstride;
    const __hip_bfloat16* xT_b  = xT + b * bstride;
    // 5) scores = (xqk_b @ xb_b^T) / 32   -> f32
    gemm_bt<float><<<dim3(TT / 128, TT / 128), 256, 0, stream>>>(
        xqk_b, xb_b, scores, TT, TT, DD, 0.03125f);
    // 6) attn = softmax_rows(scores) -> bf16
    softmax_rows_k<<<TT, 256, 0, stream>>>(scores, attn, TT);
    // 7) av_b = attn @ x_b   (Bt = xT_b [D][T]) ; overwrites dead xqk_b slot
    gemm_bt<__hip_bfloat16><<<dim3(TT / 128, DD / 128), 256, 0, stream>>>(
        attn, xT_b, xqk + b * bstride, TT, DD, TT, 1.0f);
  }

  // 8) out = av @ VO   (A = av (=xqk buffer) [16384,1024], Bt = VOT)
  gemm_bt<float><<<dim3(NTOK / 128, DD / 128), 256, 0, stream>>>(
      xqk, VOT, out, (int)NTOK, DD, DD, 1.0f);
}

// Round 2
// 459.667 us; speedup vs baseline: 1.4683x; 1.4683x over previous
//
#include <hip/hip_runtime.h>
#include <hip/hip_bf16.h>

// MergedLinearFormer: out = softmax((x@QK)@x^T / sqrt(D)) @ x @ VO
// B=4, T=4096, D=1024. 256^2-tile deep-pipelined bf16 MFMA GEMM (T2+T3+T4+T5).

#define BB 4
#define TT 4096
#define DD 1024

typedef __attribute__((ext_vector_type(8))) short bf16x8;
typedef __attribute__((ext_vector_type(4))) float f32x4;

__device__ __forceinline__ void gll16(const void* g, void* l) {
  __builtin_amdgcn_global_load_lds(
      (__attribute__((address_space(1))) void*)g,
      (__attribute__((address_space(3))) void*)l, 16, 0, 0);
}

#define WAIT_VM(n) asm volatile("s_waitcnt vmcnt(" #n ")" ::: "memory")
#define WAIT_LGKM0 do { asm volatile("s_waitcnt lgkmcnt(0)" ::: "memory"); \
                        __builtin_amdgcn_sched_barrier(0); } while (0)
#define BARRIER    do { __builtin_amdgcn_s_barrier(); \
                        __builtin_amdgcn_sched_barrier(0); } while (0)

// ---------------- cast f32 -> bf16 (8 elems/thread) -------------------------
__global__ __launch_bounds__(256) void cast_bf16_k(const float* __restrict__ in,
                                                   __hip_bfloat16* __restrict__ out,
                                                   long n) {
  long i = ((long)blockIdx.x * 256 + threadIdx.x) * 8;
  if (i + 8 > n) return;
  float4 f0 = *(const float4*)(in + i);
  float4 f1 = *(const float4*)(in + i + 4);
  union { __hip_bfloat16 h[8]; uint4 v; } u;
  u.h[0] = __float2bfloat16(f0.x); u.h[1] = __float2bfloat16(f0.y);
  u.h[2] = __float2bfloat16(f0.z); u.h[3] = __float2bfloat16(f0.w);
  u.h[4] = __float2bfloat16(f1.x); u.h[5] = __float2bfloat16(f1.y);
  u.h[6] = __float2bfloat16(f1.z); u.h[7] = __float2bfloat16(f1.w);
  *(uint4*)(out + i) = u.v;
}

// ------------- transpose + cast: in f32 [R][C] -> out bf16 [C][R] -----------
__global__ __launch_bounds__(256) void transpose_cast_k(const float* __restrict__ in,
                                                        __hip_bfloat16* __restrict__ out,
                                                        int R, int C,
                                                        long in_bstride, long out_bstride) {
  in  += (long)blockIdx.z * in_bstride;
  out += (long)blockIdx.z * out_bstride;
  __shared__ __hip_bfloat16 tile[64][65];
  int c0 = blockIdx.x * 64, r0 = blockIdx.y * 64;
  int tx = threadIdx.x & 63, ty = threadIdx.x >> 6;
#pragma unroll
  for (int i = 0; i < 16; ++i) {
    int r = ty + i * 4;
    tile[r][tx] = __float2bfloat16(in[(long)(r0 + r) * C + c0 + tx]);
  }
  __syncthreads();
#pragma unroll
  for (int i = 0; i < 16; ++i) {
    int c = ty + i * 4;
    out[(long)(c0 + c) * R + r0 + tx] = tile[tx][c];
  }
}

// ------- GEMM: C[M,N] = alpha * A[M,K] @ Bt[N,K]^T  (256x256 tile, BK=32) ---
// 8 waves (2Mx4N), per-wave 128x64 = 8x4 16x16x32 frags. LDS: 4-buffer ring,
// 32KB each (A 16KB + B 16KB). Prefetch distance 3, counted vmcnt(8).
// Swizzle: 16B slot s ^= (row>>1)&3, applied on pre-swizzled global source
// (linear global_load_lds dest) AND on ds_read address (rule #21).
template <typename OUT_T>
__global__ __launch_bounds__(512, 2) void gemm256(
    const __hip_bfloat16* __restrict__ A,
    const __hip_bfloat16* __restrict__ Bt,
    OUT_T* __restrict__ C,
    int M, int N, int K, float alpha,
    long sAz, long sBz, long sCz) {
  __shared__ alignas(16) char smem[131072];
  A  += (long)blockIdx.z * sAz;
  Bt += (long)blockIdx.z * sBz;
  C  += (long)blockIdx.z * sCz;

  const int tid  = threadIdx.x;
  const int lane = tid & 63;
  const int wid  = tid >> 6;
  const int wr   = wid >> 2;        // 0..1
  const int wc   = wid & 3;         // 0..3
  const long m0 = (long)blockIdx.x * 256;
  const long n0 = (long)blockIdx.y * 256;
  const int NT = K >> 5;            // K-tiles of 32 (NT >= 4 required)

  // staging: thread -> row (tid>>2), 16B slot (tid&3), source slot pre-swizzled
  const int st_slot = (tid & 3) ^ ((tid >> 3) & 3);
  const __hip_bfloat16* gA = A  + (m0 + (tid >> 2)) * (long)K + st_slot * 8;
  const __hip_bfloat16* gB = Bt + (n0 + (tid >> 2)) * (long)K + st_slot * 8;

#define STAGE_A(tt) do { const int bi_ = (tt) & 3; const long ko_ = (long)(tt) * 32; \
    gll16(gA + ko_,                 smem + bi_ * 32768 +        wid * 1024);         \
    gll16(gA + 128 * (long)K + ko_, smem + bi_ * 32768 + 8192 + wid * 1024); } while (0)
#define STAGE_B(tt) do { const int bi_ = (tt) & 3; const long ko_ = (long)(tt) * 32; \
    gll16(gB + ko_,                 smem + bi_ * 32768 + 16384 +        wid * 1024); \
    gll16(gB + 128 * (long)K + ko_, smem + bi_ * 32768 + 16384 + 8192 + wid * 1024); } while (0)

  // fragment read offsets (swizzled): row r, 16B slot (lane>>4)^((r>>1)&3)
  const int fr   = lane & 15;
  const int sw16 = (((lane >> 4) ^ ((lane >> 1) & 3)) << 4);
  const int aoff = (wr * 128 + fr) * 64 + sw16;          // + mi*1024
  const int boff = 16384 + (wc * 64 + fr) * 64 + sw16;   // + ni*1024

  f32x4 acc[8][4];
#pragma unroll
  for (int mi = 0; mi < 8; ++mi)
#pragma unroll
    for (int ni = 0; ni < 4; ++ni)
      acc[mi][ni] = (f32x4){0.f, 0.f, 0.f, 0.f};

  // prologue: stage tiles 0,1,2; wait for tile 0 (oldest 4 of 12)
  STAGE_A(0); STAGE_B(0);
  STAGE_A(1); STAGE_B(1);
  STAGE_A(2); STAGE_B(2);
  WAIT_VM(8);
  BARRIER;

  for (int t = 0; t < NT; ++t) {
    const char* bA = smem + (t & 3) * 32768;
    bf16x8 aq[4], bq[4];
    // ---- phase 0: C-rows mi 0..3 ----
#pragma unroll
    for (int ni = 0; ni < 4; ++ni) bq[ni] = *(const bf16x8*)(bA + boff + ni * 1024);
#pragma unroll
    for (int mi = 0; mi < 4; ++mi) aq[mi] = *(const bf16x8*)(bA + aoff + mi * 1024);
    if (t + 3 < NT) STAGE_A(t + 3);
    BARRIER;
    WAIT_LGKM0;
    __builtin_amdgcn_s_setprio(1);
#pragma unroll
    for (int mi = 0; mi < 4; ++mi)
#pragma unroll
      for (int ni = 0; ni < 4; ++ni)
        acc[mi][ni] = __builtin_amdgcn_mfma_f32_16x16x32_bf16(aq[mi], bq[ni], acc[mi][ni], 0, 0, 0);
    __builtin_amdgcn_s_setprio(0);
    BARRIER;
    // ---- phase 1: C-rows mi 4..7 ----
#pragma unroll
    for (int mi = 0; mi < 4; ++mi) aq[mi] = *(const bf16x8*)(bA + aoff + (4 + mi) * 1024);
    if (t + 3 < NT) STAGE_B(t + 3);
    // counted wait: tile t+1's 4 loads are the oldest in flight
    if (t + 3 < NT)      { WAIT_VM(8); }
    else if (t + 2 < NT) { WAIT_VM(4); }
    else if (t + 1 < NT) { WAIT_VM(0); }
    BARRIER;
    WAIT_LGKM0;
    __builtin_amdgcn_s_setprio(1);
#pragma unroll
    for (int mi = 0; mi < 4; ++mi)
#pragma unroll
      for (int ni = 0; ni < 4; ++ni)
        acc[4 + mi][ni] = __builtin_amdgcn_mfma_f32_16x16x32_bf16(aq[mi], bq[ni], acc[4 + mi][ni], 0, 0, 0);
    __builtin_amdgcn_s_setprio(0);
    BARRIER;
  }

  // epilogue: C/D layout col=lane&15, row=(lane>>4)*4+reg  [verified m89]
#pragma unroll
  for (int mi = 0; mi < 8; ++mi)
#pragma unroll
    for (int ni = 0; ni < 4; ++ni)
#pragma unroll
      for (int r = 0; r < 4; ++r) {
        long row = m0 + wr * 128 + mi * 16 + ((lane >> 4) << 2) + r;
        long col = n0 + wc * 64 + ni * 16 + fr;
        float v = acc[mi][ni][r] * alpha;
        if constexpr (sizeof(OUT_T) == 4)
          C[row * (long)N + col] = v;
        else
          C[row * (long)N + col] = __float2bfloat16(v);
      }
#undef STAGE_A
#undef STAGE_B
}

// ------------- row softmax: scores f32 [T][T] -> attn bf16 [T][T] -----------
__global__ __launch_bounds__(256) void softmax_rows_k(const float* __restrict__ S,
                                                      __hip_bfloat16* __restrict__ P,
                                                      int T) {
  const long row = blockIdx.x;
  const float* s = S + row * (long)T;
  __hip_bfloat16* p = P + row * (long)T;
  const int tid = threadIdx.x;
  __shared__ float red[8];

  float v[16];
  float m = -1e30f;
#pragma unroll
  for (int i = 0; i < 16; ++i) {
    v[i] = s[tid + i * 256];
    m = fmaxf(m, v[i]);
  }
#pragma unroll
  for (int off = 32; off >= 1; off >>= 1) m = fmaxf(m, __shfl_xor(m, off));
  if ((tid & 63) == 0) red[tid >> 6] = m;
  __syncthreads();
  m = fmaxf(fmaxf(red[0], red[1]), fmaxf(red[2], red[3]));

  float l = 0.f;
#pragma unroll
  for (int i = 0; i < 16; ++i) {
    v[i] = __expf(v[i] - m);
    l += v[i];
  }
#pragma unroll
  for (int off = 32; off >= 1; off >>= 1) l += __shfl_xor(l, off);
  if ((tid & 63) == 0) red[4 + (tid >> 6)] = l;
  __syncthreads();
  l = red[4] + red[5] + red[6] + red[7];
  const float inv = 1.0f / l;
#pragma unroll
  for (int i = 0; i < 16; ++i)
    p[tid + i * 256] = __float2bfloat16(v[i] * inv);
}

// ------------------------------- launch -------------------------------------
extern "C" void kernel_launch(void* const* d_in, const int* in_sizes, int n_in,
                              void* d_out, int out_size, void* d_ws, size_t ws_size,
                              hipStream_t stream) {
  const float* x  = (const float*)d_in[0];
  const float* QK = (const float*)d_in[1];
  const float* VO = (const float*)d_in[2];
  char* ws = (char*)d_ws;

  const long MB = 1l << 20;
  __hip_bfloat16* QKT  = (__hip_bfloat16*)(ws);            //  2 MB  QK^T
  __hip_bfloat16* VOT  = (__hip_bfloat16*)(ws + 2 * MB);   //  2 MB  VO^T
  __hip_bfloat16* xb   = (__hip_bfloat16*)(ws + 4 * MB);   // 32 MB  x bf16; later av
  __hip_bfloat16* xT   = (__hip_bfloat16*)(ws + 36 * MB);  // 32 MB  x^T per batch
  __hip_bfloat16* attn = (__hip_bfloat16*)(ws + 68 * MB);  // 128 MB [B][T][T]; xqk_b aliased
  float* scores = (float*)d_out;                           // T*T f32 == out_size exactly
  // total ws: 196 MB (== round-1 proven footprint)

  const long NTOK = (long)BB * TT;
  const long bstride = (long)TT * DD;
  const long aslot = (long)TT * TT;

  // 1) prep
  cast_bf16_k<<<(int)(NTOK * DD / (256 * 8)), 256, 0, stream>>>(x, xb, NTOK * DD);
  transpose_cast_k<<<dim3(16, 16, 1), 256, 0, stream>>>(QK, QKT, DD, DD, 0, 0);
  transpose_cast_k<<<dim3(16, 16, 1), 256, 0, stream>>>(VO, VOT, DD, DD, 0, 0);
  transpose_cast_k<<<dim3(DD / 64, TT / 64, BB), 256, 0, stream>>>(x, xT, TT, DD, bstride, bstride);

  // 2) xqk_b = xb_b @ QK   (xqk_b aliased into attn slot b, z-batched)
  gemm256<__hip_bfloat16><<<dim3(TT / 256, DD / 256, BB), 512, 0, stream>>>(
      xb, QKT, attn, TT, DD, DD, 1.0f, bstride, 0, aslot);

  // 3) per batch: scores (into d_out) -> softmax -> attn_b (overwrites xqk_b)
  for (int b = 0; b < BB; ++b) {
    gemm256<float><<<dim3(TT / 256, TT / 256, 1), 512, 0, stream>>>(
        attn + b * aslot, xb + b * bstride, scores, TT, TT, DD, 0.03125f, 0, 0, 0);
    softmax_rows_k<<<TT, 256, 0, stream>>>(scores, attn + b * aslot, TT);
  }

  // 4) av_b = attn_b @ x_b  (z-batched, writes into xb -- x bf16 is dead now)
  gemm256<__hip_bfloat16><<<dim3(TT / 256, DD / 256, BB), 512, 0, stream>>>(
      attn, xT, xb, TT, DD, TT, 1.0f, aslot, bstride, bstride);

  // 5) out = av @ VO  (flat M=16384, overwrites scores scratch in d_out)
  gemm256<float><<<dim3((int)(NTOK / 256), DD / 256, 1), 512, 0, stream>>>(
      xb, VOT, (float*)d_out, (int)NTOK, DD, DD, 1.0f, 0, 0, 0);
}

// Round 3
// 438.374 us; speedup vs baseline: 1.5396x; 1.0486x over previous
//
#include <hip/hip_runtime.h>
#include <hip/hip_bf16.h>

// MergedLinearFormer: out = softmax((x@QK)@x^T / sqrt(D)) @ x @ VO
// B=4, T=4096, D=1024. 256^2-tile, BK=64, 8-phase m201-style bf16 MFMA GEMM.

#define BB 4
#define TT 4096
#define DD 1024

typedef __attribute__((ext_vector_type(8))) short bf16x8;
typedef __attribute__((ext_vector_type(4))) float f32x4;

__device__ __forceinline__ void gll16(const void* g, void* l) {
  __builtin_amdgcn_global_load_lds(
      (__attribute__((address_space(1))) void*)g,
      (__attribute__((address_space(3))) void*)l, 16, 0, 0);
}

#define WAIT_VM(n) asm volatile("s_waitcnt vmcnt(" #n ")" ::: "memory")
#define WAIT_LGKM0 do { asm volatile("s_waitcnt lgkmcnt(0)" ::: "memory"); \
                        __builtin_amdgcn_sched_barrier(0); } while (0)
#define BARRIER    do { __builtin_amdgcn_s_barrier(); \
                        __builtin_amdgcn_sched_barrier(0); } while (0)

// ---------------- cast f32 -> bf16 (8 elems/thread) -------------------------
__global__ __launch_bounds__(256) void cast_bf16_k(const float* __restrict__ in,
                                                   __hip_bfloat16* __restrict__ out,
                                                   long n) {
  long i = ((long)blockIdx.x * 256 + threadIdx.x) * 8;
  if (i + 8 > n) return;
  float4 f0 = *(const float4*)(in + i);
  float4 f1 = *(const float4*)(in + i + 4);
  union { __hip_bfloat16 h[8]; uint4 v; } u;
  u.h[0] = __float2bfloat16(f0.x); u.h[1] = __float2bfloat16(f0.y);
  u.h[2] = __float2bfloat16(f0.z); u.h[3] = __float2bfloat16(f0.w);
  u.h[4] = __float2bfloat16(f1.x); u.h[5] = __float2bfloat16(f1.y);
  u.h[6] = __float2bfloat16(f1.z); u.h[7] = __float2bfloat16(f1.w);
  *(uint4*)(out + i) = u.v;
}

// ------------- transpose + cast: in f32 [R][C] -> out bf16 [C][R] -----------
__global__ __launch_bounds__(256) void transpose_cast_k(const float* __restrict__ in,
                                                        __hip_bfloat16* __restrict__ out,
                                                        int R, int C,
                                                        long in_bstride, long out_bstride) {
  in  += (long)blockIdx.z * in_bstride;
  out += (long)blockIdx.z * out_bstride;
  __shared__ __hip_bfloat16 tile[64][65];
  int c0 = blockIdx.x * 64, r0 = blockIdx.y * 64;
  int tx = threadIdx.x & 63, ty = threadIdx.x >> 6;
#pragma unroll
  for (int i = 0; i < 16; ++i) {
    int r = ty + i * 4;
    tile[r][tx] = __float2bfloat16(in[(long)(r0 + r) * C + c0 + tx]);
  }
  __syncthreads();
#pragma unroll
  for (int i = 0; i < 16; ++i) {
    int c = ty + i * 4;
    out[(long)(c0 + c) * R + r0 + tx] = tile[tx][c];
  }
}

// ------- GEMM: C[M,N] = alpha * A[M,K] @ Bt[N,K]^T  (256x256, BK=64) --------
// 8 waves (2Mx4N), per-wave 128x64 out = 8x4 16x16x32 frags, 2 k32-steps.
// LDS: 2 buffers x (A 32KB + B 32KB). 8 phases / 2 K-tiles, 16 MFMA each.
// Swizzle: 16B phys slot = logical ^ (row&7); pre-swizzled global source for
// global_load_lds (linear dest) + swizzled ds_read address (rule #21).
// vmcnt(8) only at phases 4/8, draining loads issued 4-5 phases earlier.
template <typename OUT_T>
__global__ __launch_bounds__(512, 2) void gemm256(
    const __hip_bfloat16* __restrict__ A,
    const __hip_bfloat16* __restrict__ Bt,
    OUT_T* __restrict__ C,
    int M, int N, int K, float alpha,
    long sAz, long sBz, long sCz) {
  __shared__ alignas(16) char smem[131072];
  A  += (long)blockIdx.z * sAz;
  Bt += (long)blockIdx.z * sBz;
  C  += (long)blockIdx.z * sCz;

  const int tid  = threadIdx.x;
  const int lane = tid & 63;
  const int wid  = tid >> 6;
  const int wr   = wid >> 2;        // 0..1
  const int wc   = wid & 3;         // 0..3
  const long m0 = (long)blockIdx.x * 256;
  const long n0 = (long)blockIdx.y * 256;
  const int NT = K >> 6;            // BK=64 K-tiles; NT even, >= 4

  // ---- staging: thread -> row (tid>>3), phys slot (tid&7), swizzled source
  const int srow = tid >> 3;
  const int sswz = (tid & 7) ^ (srow & 7);
  const __hip_bfloat16* gA = A  + (m0 + srow) * (long)K + sswz * 8;
  const __hip_bfloat16* gB = Bt + (n0 + srow) * (long)K + sswz * 8;

  // STG(op, tile s, rowgroup c, buf byte-offset D): rows c*64+(tid>>3)
#define STG_A(s, c, D) gll16(gA + (long)(c) * 64 * K + (long)(s) * 64, \
                             smem + (D) + (c) * 8192 + wid * 1024)
#define STG_B(s, c, D) gll16(gB + (long)(c) * 64 * K + (long)(s) * 64, \
                             smem + (D) + 32768 + (c) * 8192 + wid * 1024)

  // ---- ds_read bases (loop-invariant; offsets are mi/ni*2048 immediates)
  const int fr = lane & 15, l4 = lane >> 4, f7 = lane & 7;
  const char* a00 = smem +         (wr * 128 + fr) * 128 + ((l4    ) ^ f7) * 16;
  const char* a01 = smem +         (wr * 128 + fr) * 128 + ((4 | l4) ^ f7) * 16;
  const char* b00 = smem + 32768 + (wc * 64  + fr) * 128 + ((l4    ) ^ f7) * 16;
  const char* b01 = smem + 32768 + (wc * 64  + fr) * 128 + ((4 | l4) ^ f7) * 16;
  const char* a10 = a00 + 65536; const char* a11 = a01 + 65536;
  const char* b10 = b00 + 65536; const char* b11 = b01 + 65536;

  bf16x8 aq[4][2], bq[4][2];
#define RD_A(p0, p1, MIOFF)                                         \
  _Pragma("unroll") for (int mi_ = 0; mi_ < 4; ++mi_) {             \
    aq[mi_][0] = *(const bf16x8*)((p0) + ((MIOFF) + mi_) * 2048);   \
    aq[mi_][1] = *(const bf16x8*)((p1) + ((MIOFF) + mi_) * 2048);   \
  }
#define RD_B(p0, p1, NI0)                                           \
  _Pragma("unroll") for (int ni_ = 0; ni_ < 2; ++ni_) {             \
    bq[(NI0) + ni_][0] = *(const bf16x8*)((p0) + ((NI0) + ni_) * 2048); \
    bq[(NI0) + ni_][1] = *(const bf16x8*)((p1) + ((NI0) + ni_) * 2048); \
  }

  f32x4 acc[8][4];
#pragma unroll
  for (int mi = 0; mi < 8; ++mi)
#pragma unroll
    for (int ni = 0; ni < 4; ++ni)
      acc[mi][ni] = (f32x4){0.f, 0.f, 0.f, 0.f};

#define MFMA16(MI0, NI0)                                                       \
  do {                                                                         \
    __builtin_amdgcn_s_setprio(1);                                             \
    _Pragma("unroll") for (int mi_ = 0; mi_ < 4; ++mi_)                        \
    _Pragma("unroll") for (int ni_ = 0; ni_ < 2; ++ni_)                        \
    _Pragma("unroll") for (int ks_ = 0; ks_ < 2; ++ks_)                        \
      acc[(MI0) + mi_][(NI0) + ni_] = __builtin_amdgcn_mfma_f32_16x16x32_bf16( \
          aq[mi_][ks_], bq[(NI0) + ni_][ks_], acc[(MI0) + mi_][(NI0) + ni_],   \
          0, 0, 0);                                                            \
    __builtin_amdgcn_s_setprio(0);                                             \
  } while (0)

  // ---- prologue: stage tile0 (buf0) then tile1 (buf1); drain tile0
#pragma unroll
  for (int c = 0; c < 4; ++c) STG_A(0, c, 0);
#pragma unroll
  for (int c = 0; c < 4; ++c) STG_B(0, c, 0);
#pragma unroll
  for (int c = 0; c < 4; ++c) STG_A(1, c, 65536);
#pragma unroll
  for (int c = 0; c < 4; ++c) STG_B(1, c, 65536);
  WAIT_VM(8);
  BARRIER;

  for (int t2 = 0; t2 < NT; t2 += 2) {
    const bool g = (t2 + 2 < NT);
    // ---------------- K-tile t2 (buf0) ----------------
    // phi1: A(mi0-3) + B(ni0-1), 12 reads
    RD_A(a00, a01, 0); RD_B(b00, b01, 0);
    asm volatile("s_waitcnt lgkmcnt(8)");
    BARRIER; WAIT_LGKM0; MFMA16(0, 0); BARRIER;
    // phi2: B(ni2-3)
    RD_B(b00, b01, 2);
    BARRIER; WAIT_LGKM0; MFMA16(0, 2); BARRIER;
    // phi3: A(mi4-7); stage sigma0-B (B(tau0) reads done at phi2 barrier)
    RD_A(a00, a01, 4);
    if (g) { STG_B(t2 + 2, 0, 0); STG_B(t2 + 2, 1, 0);
             STG_B(t2 + 2, 2, 0); STG_B(t2 + 2, 3, 0); }
    BARRIER; WAIT_LGKM0; MFMA16(4, 2); BARRIER;
    // phi4: no reads; stage sigma0-A; drain tau1 (oldest 8)
    if (g) { STG_A(t2 + 2, 0, 0); STG_A(t2 + 2, 1, 0);
             STG_A(t2 + 2, 2, 0); STG_A(t2 + 2, 3, 0); }
    MFMA16(4, 0);
    if (g) { WAIT_VM(8); } else { WAIT_VM(0); }
    BARRIER;
    // ---------------- K-tile t2+1 (buf1) ----------------
    // phi5
    RD_A(a10, a11, 0); RD_B(b10, b11, 0);
    asm volatile("s_waitcnt lgkmcnt(8)");
    BARRIER; WAIT_LGKM0; MFMA16(0, 0); BARRIER;
    // phi6
    RD_B(b10, b11, 2);
    BARRIER; WAIT_LGKM0; MFMA16(0, 2); BARRIER;
    // phi7: stage sigma1-B
    RD_A(a10, a11, 4);
    if (g) { STG_B(t2 + 3, 0, 65536); STG_B(t2 + 3, 1, 65536);
             STG_B(t2 + 3, 2, 65536); STG_B(t2 + 3, 3, 65536); }
    BARRIER; WAIT_LGKM0; MFMA16(4, 2); BARRIER;
    // phi8: stage sigma1-A; drain sigma0 (oldest 8)
    if (g) { STG_A(t2 + 3, 0, 65536); STG_A(t2 + 3, 1, 65536);
             STG_A(t2 + 3, 2, 65536); STG_A(t2 + 3, 3, 65536); }
    MFMA16(4, 0);
    if (g) { WAIT_VM(8); } else { WAIT_VM(0); }
    BARRIER;
  }

  // epilogue: C/D layout col=lane&15, row=(lane>>4)*4+reg  [verified m89]
#pragma unroll
  for (int mi = 0; mi < 8; ++mi)
#pragma unroll
    for (int ni = 0; ni < 4; ++ni)
#pragma unroll
      for (int r = 0; r < 4; ++r) {
        long row = m0 + wr * 128 + mi * 16 + ((lane >> 4) << 2) + r;
        long col = n0 + wc * 64 + ni * 16 + fr;
        float v = acc[mi][ni][r] * alpha;
        if constexpr (sizeof(OUT_T) == 4)
          C[row * (long)N + col] = v;
        else
          C[row * (long)N + col] = __float2bfloat16(v);
      }
#undef STG_A
#undef STG_B
#undef RD_A
#undef RD_B
#undef MFMA16
}

// ------------- row softmax: scores f32 [T][T] -> attn bf16 [T][T] -----------
__global__ __launch_bounds__(256) void softmax_rows_k(const float* __restrict__ S,
                                                      __hip_bfloat16* __restrict__ P,
                                                      int T) {
  const long row = blockIdx.x;
  const float* s = S + row * (long)T;
  __hip_bfloat16* p = P + row * (long)T;
  const int tid = threadIdx.x;
  __shared__ float red[8];

  float v[16];
  float m = -1e30f;
#pragma unroll
  for (int i = 0; i < 16; ++i) {
    v[i] = s[tid + i * 256];
    m = fmaxf(m, v[i]);
  }
#pragma unroll
  for (int off = 32; off >= 1; off >>= 1) m = fmaxf(m, __shfl_xor(m, off));
  if ((tid & 63) == 0) red[tid >> 6] = m;
  __syncthreads();
  m = fmaxf(fmaxf(red[0], red[1]), fmaxf(red[2], red[3]));

  float l = 0.f;
#pragma unroll
  for (int i = 0; i < 16; ++i) {
    v[i] = __expf(v[i] - m);
    l += v[i];
  }
#pragma unroll
  for (int off = 32; off >= 1; off >>= 1) l += __shfl_xor(l, off);
  if ((tid & 63) == 0) red[4 + (tid >> 6)] = l;
  __syncthreads();
  l = red[4] + red[5] + red[6] + red[7];
  const float inv = 1.0f / l;
#pragma unroll
  for (int i = 0; i < 16; ++i)
    p[tid + i * 256] = __float2bfloat16(v[i] * inv);
}

// ------------------------------- launch -------------------------------------
extern "C" void kernel_launch(void* const* d_in, const int* in_sizes, int n_in,
                              void* d_out, int out_size, void* d_ws, size_t ws_size,
                              hipStream_t stream) {
  const float* x  = (const float*)d_in[0];
  const float* QK = (const float*)d_in[1];
  const float* VO = (const float*)d_in[2];
  char* ws = (char*)d_ws;

  const long MB = 1l << 20;
  __hip_bfloat16* QKT  = (__hip_bfloat16*)(ws);            //  2 MB  QK^T
  __hip_bfloat16* VOT  = (__hip_bfloat16*)(ws + 2 * MB);   //  2 MB  VO^T
  __hip_bfloat16* xb   = (__hip_bfloat16*)(ws + 4 * MB);   // 32 MB  x bf16; later av
  __hip_bfloat16* xT   = (__hip_bfloat16*)(ws + 36 * MB);  // 32 MB  x^T per batch
  __hip_bfloat16* attn = (__hip_bfloat16*)(ws + 68 * MB);  // 128 MB [B][T][T]; xqk_b aliased
  float* scores = (float*)d_out;                           // T*T f32 == out_size exactly

  const long NTOK = (long)BB * TT;
  const long bstride = (long)TT * DD;
  const long aslot = (long)TT * TT;

  // 1) prep
  cast_bf16_k<<<(int)(NTOK * DD / (256 * 8)), 256, 0, stream>>>(x, xb, NTOK * DD);
  transpose_cast_k<<<dim3(16, 16, 1), 256, 0, stream>>>(QK, QKT, DD, DD, 0, 0);
  transpose_cast_k<<<dim3(16, 16, 1), 256, 0, stream>>>(VO, VOT, DD, DD, 0, 0);
  transpose_cast_k<<<dim3(DD / 64, TT / 64, BB), 256, 0, stream>>>(x, xT, TT, DD, bstride, bstride);

  // 2) xqk_b = xb_b @ QK   (xqk_b aliased into attn slot b, z-batched)
  gemm256<__hip_bfloat16><<<dim3(TT / 256, DD / 256, BB), 512, 0, stream>>>(
      xb, QKT, attn, TT, DD, DD, 1.0f, bstride, 0, aslot);

  // 3) per batch: scores (into d_out) -> softmax -> attn_b (overwrites xqk_b)
  for (int b = 0; b < BB; ++b) {
    gemm256<float><<<dim3(TT / 256, TT / 256, 1), 512, 0, stream>>>(
        attn + b * aslot, xb + b * bstride, scores, TT, TT, DD, 0.03125f, 0, 0, 0);
    softmax_rows_k<<<TT, 256, 0, stream>>>(scores, attn + b * aslot, TT);
  }

  // 4) av_b = attn_b @ x_b  (z-batched, writes into xb -- x bf16 is dead now)
  gemm256<__hip_bfloat16><<<dim3(TT / 256, DD / 256, BB), 512, 0, stream>>>(
      attn, xT, xb, TT, DD, TT, 1.0f, aslot, bstride, bstride);

  // 5) out = av @ VO  (flat M=16384, overwrites scores scratch in d_out)
  gemm256<float><<<dim3((int)(NTOK / 256), DD / 256, 1), 512, 0, stream>>>(
      xb, VOT, (float*)d_out, (int)NTOK, DD, DD, 1.0f, 0, 0, 0);
}

// Round 4
// 369.267 us; speedup vs baseline: 1.8278x; 1.1871x over previous
//
#include <hip/hip_runtime.h>
#include <hip/hip_bf16.h>

// MergedLinearFormer: out = softmax((x@QK)@x^T / sqrt(D)) @ x @ VO
// B=4, T=4096, D=1024. 256^2-tile BK=64 8-phase bf16 MFMA GEMM with fused
// exp-epilogue (softmax folded into scores GEMM + av GEMM epilogues).

#define BB 4
#define TT 4096
#define DD 1024

typedef __attribute__((ext_vector_type(8))) short bf16x8;
typedef __attribute__((ext_vector_type(4))) float f32x4;

__device__ __forceinline__ void gll16(const void* g, void* l) {
  __builtin_amdgcn_global_load_lds(
      (__attribute__((address_space(1))) void*)g,
      (__attribute__((address_space(3))) void*)l, 16, 0, 0);
}

#define WAIT_VM(n) asm volatile("s_waitcnt vmcnt(" #n ")" ::: "memory")
#define WAIT_LGKM0 do { asm volatile("s_waitcnt lgkmcnt(0)" ::: "memory"); \
                        __builtin_amdgcn_sched_barrier(0); } while (0)
#define BARRIER    do { __builtin_amdgcn_s_barrier(); \
                        __builtin_amdgcn_sched_barrier(0); } while (0)

// ---- x prep: read x f32 once, write xb (row-major bf16) + xT (col-major) ---
__global__ __launch_bounds__(256) void xprep_k(const float* __restrict__ in,
                                               __hip_bfloat16* __restrict__ rm,
                                               __hip_bfloat16* __restrict__ cm,
                                               int R, int C, long bs) {
  in += (long)blockIdx.z * bs; rm += (long)blockIdx.z * bs; cm += (long)blockIdx.z * bs;
  __shared__ __hip_bfloat16 tile[64][65];
  int c0 = blockIdx.x * 64, r0 = blockIdx.y * 64;
  int tx = threadIdx.x & 63, ty = threadIdx.x >> 6;
#pragma unroll
  for (int i = 0; i < 16; ++i) {
    int r = ty + i * 4;
    __hip_bfloat16 v = __float2bfloat16(in[(long)(r0 + r) * C + c0 + tx]);
    tile[r][tx] = v;
    rm[(long)(r0 + r) * C + c0 + tx] = v;
  }
  __syncthreads();
#pragma unroll
  for (int i = 0; i < 16; ++i) {
    int c = ty + i * 4;
    cm[(long)(c0 + c) * R + r0 + tx] = tile[tx][c];
  }
}

// ------------- transpose + cast (weights): f32 [R][C] -> bf16 [C][R] --------
__global__ __launch_bounds__(256) void transpose_cast_k(const float* __restrict__ in,
                                                        __hip_bfloat16* __restrict__ out,
                                                        int R, int C) {
  __shared__ __hip_bfloat16 tile[64][65];
  int c0 = blockIdx.x * 64, r0 = blockIdx.y * 64;
  int tx = threadIdx.x & 63, ty = threadIdx.x >> 6;
#pragma unroll
  for (int i = 0; i < 16; ++i) {
    int r = ty + i * 4;
    tile[r][tx] = __float2bfloat16(in[(long)(r0 + r) * C + c0 + tx]);
  }
  __syncthreads();
#pragma unroll
  for (int i = 0; i < 16; ++i) {
    int c = ty + i * 4;
    out[(long)(c0 + c) * R + r0 + tx] = tile[tx][c];
  }
}

__global__ __launch_bounds__(256) void zero_f32_k(float* __restrict__ p, int n) {
  int i = blockIdx.x * 256 + threadIdx.x;
  if (i < n) p[i] = 0.f;
}

// ------- GEMM: C[M,N] = f(A[M,K] @ Bt[N,K]^T)  (256x256, BK=64, 8 phases) ---
// EPI: 0 = f32*alpha, 1 = bf16*alpha, 2 = bf16 exp(alpha*v) + row-sum atomics,
//      3 = bf16 * (1/lsum[row]).
template <typename OUT_T, int EPI>
__global__ __launch_bounds__(512, 2) void gemm256(
    const __hip_bfloat16* __restrict__ A,
    const __hip_bfloat16* __restrict__ Bt,
    OUT_T* __restrict__ C,
    int M, int N, int K, float alpha,
    long sAz, long sBz, long sCz, float* __restrict__ lsum) {
  __shared__ alignas(16) char smem[131072];
  A  += (long)blockIdx.z * sAz;
  Bt += (long)blockIdx.z * sBz;
  C  += (long)blockIdx.z * sCz;

  // bijective XCD swizzle within the z-slice (nwg % 8 == 0, gridDim.x pow2)
  const int nwg = gridDim.x * gridDim.y;
  const int lin = blockIdx.x + gridDim.x * blockIdx.y;
  const int swz = (lin & 7) * (nwg >> 3) + (lin >> 3);
  const int gxsh = __popc(gridDim.x - 1);
  const int bx = swz & (gridDim.x - 1);
  const int by = swz >> gxsh;

  const int tid  = threadIdx.x;
  const int lane = tid & 63;
  const int wid  = tid >> 6;
  const int wr   = wid >> 2;        // 0..1
  const int wc   = wid & 3;         // 0..3
  const long m0 = (long)bx * 256;
  const long n0 = (long)by * 256;
  const int NT = K >> 6;            // BK=64 K-tiles; NT even, >= 4

  // staging: thread -> row (tid>>3), phys slot (tid&7), swizzled source
  const int srow = tid >> 3;
  const int sswz = (tid & 7) ^ (srow & 7);
  const __hip_bfloat16* gA = A  + (m0 + srow) * (long)K + sswz * 8;
  const __hip_bfloat16* gB = Bt + (n0 + srow) * (long)K + sswz * 8;

#define STG_A(s, c, D) gll16(gA + (long)(c) * 64 * K + (long)(s) * 64, \
                             smem + (D) + (c) * 8192 + wid * 1024)
#define STG_B(s, c, D) gll16(gB + (long)(c) * 64 * K + (long)(s) * 64, \
                             smem + (D) + 32768 + (c) * 8192 + wid * 1024)

  // ds_read bases (loop-invariant; offsets are mi/ni*2048 immediates)
  const int fr = lane & 15, l4 = lane >> 4, f7 = lane & 7;
  const char* a00 = smem +         (wr * 128 + fr) * 128 + ((l4    ) ^ f7) * 16;
  const char* a01 = smem +         (wr * 128 + fr) * 128 + ((4 | l4) ^ f7) * 16;
  const char* b00 = smem + 32768 + (wc * 64  + fr) * 128 + ((l4    ) ^ f7) * 16;
  const char* b01 = smem + 32768 + (wc * 64  + fr) * 128 + ((4 | l4) ^ f7) * 16;
  const char* a10 = a00 + 65536; const char* a11 = a01 + 65536;
  const char* b10 = b00 + 65536; const char* b11 = b01 + 65536;

  bf16x8 aq[4][2], bq[4][2];
#define RD_A(p0, p1, MIOFF)                                         \
  _Pragma("unroll") for (int mi_ = 0; mi_ < 4; ++mi_) {             \
    aq[mi_][0] = *(const bf16x8*)((p0) + ((MIOFF) + mi_) * 2048);   \
    aq[mi_][1] = *(const bf16x8*)((p1) + ((MIOFF) + mi_) * 2048);   \
  }
#define RD_B(p0, p1, NI0)                                           \
  _Pragma("unroll") for (int ni_ = 0; ni_ < 2; ++ni_) {             \
    bq[(NI0) + ni_][0] = *(const bf16x8*)((p0) + ((NI0) + ni_) * 2048); \
    bq[(NI0) + ni_][1] = *(const bf16x8*)((p1) + ((NI0) + ni_) * 2048); \
  }

  f32x4 acc[8][4];
#pragma unroll
  for (int mi = 0; mi < 8; ++mi)
#pragma unroll
    for (int ni = 0; ni < 4; ++ni)
      acc[mi][ni] = (f32x4){0.f, 0.f, 0.f, 0.f};

  // ks OUTER: 8 independent MFMAs between dependent acc pairs
#define MFMA16(MI0, NI0)                                                       \
  do {                                                                         \
    __builtin_amdgcn_s_setprio(1);                                             \
    _Pragma("unroll") for (int ks_ = 0; ks_ < 2; ++ks_)                        \
    _Pragma("unroll") for (int mi_ = 0; mi_ < 4; ++mi_)                        \
    _Pragma("unroll") for (int ni_ = 0; ni_ < 2; ++ni_)                        \
      acc[(MI0) + mi_][(NI0) + ni_] = __builtin_amdgcn_mfma_f32_16x16x32_bf16( \
          aq[mi_][ks_], bq[(NI0) + ni_][ks_], acc[(MI0) + mi_][(NI0) + ni_],   \
          0, 0, 0);                                                            \
    __builtin_amdgcn_s_setprio(0);                                             \
  } while (0)

  // prologue: stage tile0 (buf0) then tile1 (buf1); drain tile0
#pragma unroll
  for (int c = 0; c < 4; ++c) STG_A(0, c, 0);
#pragma unroll
  for (int c = 0; c < 4; ++c) STG_B(0, c, 0);
#pragma unroll
  for (int c = 0; c < 4; ++c) STG_A(1, c, 65536);
#pragma unroll
  for (int c = 0; c < 4; ++c) STG_B(1, c, 65536);
  WAIT_VM(8);
  BARRIER;

  for (int t2 = 0; t2 < NT; t2 += 2) {
    const bool g = (t2 + 2 < NT);
    // ---------------- K-tile t2 (buf0) ----------------
    RD_A(a00, a01, 0); RD_B(b00, b01, 0);
    asm volatile("s_waitcnt lgkmcnt(8)");
    BARRIER; WAIT_LGKM0; MFMA16(0, 0); BARRIER;
    RD_B(b00, b01, 2);
    BARRIER; WAIT_LGKM0; MFMA16(0, 2); BARRIER;
    RD_A(a00, a01, 4);
    if (g) { STG_B(t2 + 2, 0, 0); STG_B(t2 + 2, 1, 0);
             STG_B(t2 + 2, 2, 0); STG_B(t2 + 2, 3, 0); }
    BARRIER; WAIT_LGKM0; MFMA16(4, 2); BARRIER;
    if (g) { STG_A(t2 + 2, 0, 0); STG_A(t2 + 2, 1, 0);
             STG_A(t2 + 2, 2, 0); STG_A(t2 + 2, 3, 0); }
    MFMA16(4, 0);
    if (g) { WAIT_VM(8); } else { WAIT_VM(0); }
    BARRIER;
    // ---------------- K-tile t2+1 (buf1) ----------------
    RD_A(a10, a11, 0); RD_B(b10, b11, 0);
    asm volatile("s_waitcnt lgkmcnt(8)");
    BARRIER; WAIT_LGKM0; MFMA16(0, 0); BARRIER;
    RD_B(b10, b11, 2);
    BARRIER; WAIT_LGKM0; MFMA16(0, 2); BARRIER;
    RD_A(a10, a11, 4);
    if (g) { STG_B(t2 + 3, 0, 65536); STG_B(t2 + 3, 1, 65536);
             STG_B(t2 + 3, 2, 65536); STG_B(t2 + 3, 3, 65536); }
    BARRIER; WAIT_LGKM0; MFMA16(4, 2); BARRIER;
    if (g) { STG_A(t2 + 3, 0, 65536); STG_A(t2 + 3, 1, 65536);
             STG_A(t2 + 3, 2, 65536); STG_A(t2 + 3, 3, 65536); }
    MFMA16(4, 0);
    if (g) { WAIT_VM(8); } else { WAIT_VM(0); }
    BARRIER;
  }

  // ---- epilogue: C/D layout col=lane&15, row=(lane>>4)*4+reg [verified m89]
  if constexpr (EPI == 2) {
    // P = exp(alpha*v) in bf16 + per-row sums -> lsum atomics
    float* lred = (float*)smem;
    __syncthreads();
    for (int i = tid; i < 1024; i += 512) lred[i] = 0.f;
    __syncthreads();
#pragma unroll
    for (int mi = 0; mi < 8; ++mi) {
#pragma unroll
      for (int r = 0; r < 4; ++r) {
        const int rloc = wr * 128 + mi * 16 + (l4 << 2) + r;
        const long row = m0 + rloc;
        float rs = 0.f;
#pragma unroll
        for (int ni = 0; ni < 4; ++ni) {
          float e = __expf(acc[mi][ni][r] * alpha);
          long col = n0 + wc * 64 + ni * 16 + fr;
          C[row * (long)N + col] = (OUT_T)__float2bfloat16(e);
          rs += e;
        }
        rs += __shfl_xor(rs, 1); rs += __shfl_xor(rs, 2);
        rs += __shfl_xor(rs, 4); rs += __shfl_xor(rs, 8);
        if (fr == 0) lred[rloc * 4 + wc] = rs;
      }
    }
    __syncthreads();
    if (tid < 256) {
      float s4 = lred[tid * 4] + lred[tid * 4 + 1] + lred[tid * 4 + 2] + lred[tid * 4 + 3];
      atomicAdd(&lsum[(long)blockIdx.z * M + m0 + tid], s4);
    }
  } else if constexpr (EPI == 3) {
#pragma unroll
    for (int mi = 0; mi < 8; ++mi) {
      const long row = m0 + wr * 128 + mi * 16 + (l4 << 2);
      float4 lv = *(const float4*)&lsum[(long)blockIdx.z * M + row];
      float inv[4] = {1.f / lv.x, 1.f / lv.y, 1.f / lv.z, 1.f / lv.w};
#pragma unroll
      for (int ni = 0; ni < 4; ++ni) {
        long col = n0 + wc * 64 + ni * 16 + fr;
#pragma unroll
        for (int r = 0; r < 4; ++r)
          C[(row + r) * (long)N + col] = (OUT_T)__float2bfloat16(acc[mi][ni][r] * inv[r]);
      }
    }
  } else {
#pragma unroll
    for (int mi = 0; mi < 8; ++mi)
#pragma unroll
      for (int ni = 0; ni < 4; ++ni)
#pragma unroll
        for (int r = 0; r < 4; ++r) {
          long row = m0 + wr * 128 + mi * 16 + (l4 << 2) + r;
          long col = n0 + wc * 64 + ni * 16 + fr;
          float v = acc[mi][ni][r] * alpha;
          if constexpr (EPI == 0)
            C[row * (long)N + col] = v;
          else
            C[row * (long)N + col] = (OUT_T)__float2bfloat16(v);
        }
  }
#undef STG_A
#undef STG_B
#undef RD_A
#undef RD_B
#undef MFMA16
}

// ------------------------------- launch -------------------------------------
extern "C" void kernel_launch(void* const* d_in, const int* in_sizes, int n_in,
                              void* d_out, int out_size, void* d_ws, size_t ws_size,
                              hipStream_t stream) {
  const float* x  = (const float*)d_in[0];
  const float* QK = (const float*)d_in[1];
  const float* VO = (const float*)d_in[2];
  char* ws = (char*)d_ws;

  const long MB = 1l << 20;
  __hip_bfloat16* QKT  = (__hip_bfloat16*)(ws);            //  2 MB  QK^T (dead after xqk)
  float*          lsum = (float*)(ws);                     //  64 KB [B][T], reuses QKT slot
  __hip_bfloat16* VOT  = (__hip_bfloat16*)(ws + 2 * MB);   //  2 MB  VO^T
  __hip_bfloat16* xb   = (__hip_bfloat16*)(ws + 4 * MB);   // 32 MB  x bf16; later av
  __hip_bfloat16* xT   = (__hip_bfloat16*)(ws + 36 * MB);  // 32 MB  x^T per batch
  __hip_bfloat16* attn = (__hip_bfloat16*)(ws + 68 * MB);  // 128 MB [B][T][T] = P (exp'd)
  __hip_bfloat16* xqk  = (__hip_bfloat16*)d_out;           // 32 MB of the 64 MB d_out

  const long NTOK = (long)BB * TT;
  const long bstride = (long)TT * DD;
  const long aslot = (long)TT * TT;

  // 1) prep: x -> xb + xT in one pass; weight transposes
  xprep_k<<<dim3(DD / 64, TT / 64, BB), 256, 0, stream>>>(x, xb, xT, TT, DD, bstride);
  transpose_cast_k<<<dim3(16, 16, 1), 256, 0, stream>>>(QK, QKT, DD, DD);
  transpose_cast_k<<<dim3(16, 16, 1), 256, 0, stream>>>(VO, VOT, DD, DD);

  // 2) xqk_b = xb_b @ QK -> bf16 into d_out
  gemm256<__hip_bfloat16, 1><<<dim3(TT / 256, DD / 256, BB), 512, 0, stream>>>(
      xb, QKT, xqk, TT, DD, DD, 1.0f, bstride, 0, bstride, nullptr);

  // 3) lsum = 0 (QKT slot is dead now)
  zero_f32_k<<<(int)(NTOK / 256), 256, 0, stream>>>(lsum, (int)NTOK);

  // 4) P = exp(xqk @ xb^T / 32), row sums -> lsum  (z-batched, no softmax pass)
  gemm256<__hip_bfloat16, 2><<<dim3(TT / 256, TT / 256, BB), 512, 0, stream>>>(
      xqk, xb, attn, TT, TT, DD, 0.03125f, bstride, bstride, aslot, lsum);

  // 5) av_b = (P_b @ x_b) / lsum  (z-batched, writes into xb -- x dead now)
  gemm256<__hip_bfloat16, 3><<<dim3(TT / 256, DD / 256, BB), 512, 0, stream>>>(
      attn, xT, xb, TT, DD, TT, 1.0f, aslot, bstride, bstride, lsum);

  // 6) out = av @ VO  (flat M=16384, overwrites xqk region of d_out)
  gemm256<float, 0><<<dim3((int)(NTOK / 256), DD / 256, 1), 512, 0, stream>>>(
      xb, VOT, (float*)d_out, (int)NTOK, DD, DD, 1.0f, 0, 0, 0, nullptr);
}